// Round 7
// baseline (271.834 us; speedup 1.0000x reference)
//
#include <hip/hip_runtime.h>
#include <cstdint>
#include <cstddef>

#define NNODES 20000
#define NEDGES 160000
#define DFEAT  128
#define NEXP   4

typedef unsigned short u16;
typedef __attribute__((ext_vector_type(8))) short short8v;   // 8 bf16 (4 VGPRs)
typedef __attribute__((ext_vector_type(4))) float float4v;   // 4 f32 acc

static __device__ __forceinline__ u16 f2bf(float f) {
    union { float f; unsigned int i; } v; v.f = f;
    unsigned int r = (v.i + 0x7FFFu + ((v.i >> 16) & 1u)) >> 16;  // RNE
    return (u16)r;
}
static __device__ __forceinline__ float lo2f(unsigned int u) { return __uint_as_float(u << 16); }
static __device__ __forceinline__ float hi2f(unsigned int u) { return __uint_as_float(u & 0xFFFF0000u); }

// ---------------- workspace layout (float-element offsets; all 16B-aligned) --
// deg        0        [20000]  (zeroed)
// cursor     20000    [20000]  (zeroed)
// importance 40000    [8]      (zeroed)
// rowstart   40960    [20001] int
// csrc       61440    [160000] int
// cnrm       221440   [160000]
// gates      381440   [80000]
// W1t        461440   (65536 u16)  bf16 [4][128c][128k]
// W2t        494208   (65536 u16)
// aggx       526976   (2.56M u16)  bf16 [20000][128]
// h          1806976  (10.24M u16) bf16 [4][20000][128]
// aggh       6926976  (10.24M u16) bf16 [4][20000][128]

// ------------- fused independent pre-work: deg | transpose(W,LDS) | gate -----
// blocks [0,625): degree; [625,753): weight transpose tiles; [753,832): gate
__global__ void k_pre(const int* __restrict__ ei,
                      const float* __restrict__ W1, const float* __restrict__ W2,
                      const float* __restrict__ x_agg, const float* __restrict__ w_gate,
                      const float* __restrict__ thr, const float* __restrict__ mask,
                      float* __restrict__ deg, u16* __restrict__ W1t, u16* __restrict__ W2t,
                      float* __restrict__ gates, float* __restrict__ importance) {
    int b = blockIdx.x;
    if (b < 625) {                       // ---- degree histogram
        int e = b * 256 + threadIdx.x;
        if (e < NEDGES) atomicAdd(&deg[ei[NEDGES + e]], 1.0f);
        return;
    }
    if (b < 753) {                       // ---- coalesced transpose + bf16 cast
        __shared__ u16 tile[32][33];
        int tb = b - 625;                // 0..127
        int arr = tb >> 6;               // W1 or W2
        int t6 = tb & 63;                // e(2) | ktile(2) | ctile(2)
        int e  = t6 >> 4;
        int kt = (t6 >> 2) & 3;
        int ct = t6 & 3;
        const float* W = arr ? W2 : W1;
        u16* Wt = arr ? W2t : W1t;
        int ty = threadIdx.x >> 5, tx = threadIdx.x & 31;
#pragma unroll
        for (int r = 0; r < 4; ++r) {    // read W[k][c] coalesced in c
            int k = kt * 32 + ty + r * 8;
            int c = ct * 32 + tx;
            tile[ty + r * 8][tx] = f2bf(W[(size_t)e * 16384 + (size_t)k * 128 + c]);
        }
        __syncthreads();
#pragma unroll
        for (int r = 0; r < 4; ++r) {    // write Wt[c][k] coalesced in k
            int c = ct * 32 + ty + r * 8;
            int k = kt * 32 + tx;
            Wt[(size_t)e * 16384 + (size_t)c * 128 + k] = tile[tx][ty + r * 8];
        }
        return;
    }
    // ---- gating (f32 exact)
    int n = (b - 753) * 256 + threadIdx.x;
    float4 lg = make_float4(0.f, 0.f, 0.f, 0.f);
    if (n < NNODES) {
        const float4* xr = (const float4*)(x_agg + (size_t)n * DFEAT);
        const float4* wg = (const float4*)w_gate;
        for (int k4 = 0; k4 < 32; ++k4) {
            float4 xv = xr[k4];
            float4 w0 = wg[4 * k4 + 0], w1 = wg[4 * k4 + 1];
            float4 w2 = wg[4 * k4 + 2], w3 = wg[4 * k4 + 3];
            lg.x += xv.x * w0.x + xv.y * w1.x + xv.z * w2.x + xv.w * w3.x;
            lg.y += xv.x * w0.y + xv.y * w1.y + xv.z * w2.y + xv.w * w3.y;
            lg.z += xv.x * w0.z + xv.y * w1.z + xv.z * w2.z + xv.w * w3.z;
            lg.w += xv.x * w0.w + xv.y * w1.w + xv.z * w2.w + xv.w * w3.w;
        }
    }
    float g[4];
    float lv[4] = {lg.x, lg.y, lg.z, lg.w};
    for (int e = 0; e < 4; ++e) {
        float sgm = 1.0f / (1.0f + expf(-lv[e]));
        g[e] = (sgm - thr[e] > 0.0f) ? mask[e] : 0.0f;
        if (n >= NNODES) g[e] = 0.0f;
    }
    if (n < NNODES) ((float4*)gates)[n] = make_float4(g[0], g[1], g[2], g[3]);
    int lane = threadIdx.x & 63;
    for (int e = 0; e < 4; ++e) {
        float v = g[e];
        for (int off = 32; off >= 1; off >>= 1) v += __shfl_down(v, off);
        if (lane == 0) atomicAdd(&importance[e], v);
    }
}

// ------------------------------------------------- exclusive scan (1 block)
__global__ void k_scan(const float* __restrict__ deg, int* __restrict__ rowstart) {
    __shared__ int part[1024];
    int t = threadIdx.x;
    const int PER = 20;
    int base = t * PER;
    int s = 0;
    for (int i = 0; i < PER; ++i) {
        int n = base + i;
        if (n < NNODES) s += (int)deg[n];
    }
    part[t] = s;
    __syncthreads();
    for (int off = 1; off < 1024; off <<= 1) {
        int v = (t >= off) ? part[t - off] : 0;
        __syncthreads();
        part[t] += v;
        __syncthreads();
    }
    int run = part[t] - s;
    for (int i = 0; i < PER; ++i) {
        int n = base + i;
        if (n < NNODES) {
            rowstart[n] = run;
            run += (int)deg[n];
        }
    }
    if (t == 1023) rowstart[NNODES] = part[1023];
}

// ------------------------------------------------------- CSR fill + norm
__global__ void k_fill(const int* __restrict__ ei, const float* __restrict__ deg,
                       const int* __restrict__ rowstart, int* __restrict__ cursor,
                       int* __restrict__ csrc, float* __restrict__ cnrm) {
    int e = blockIdx.x * 256 + threadIdx.x;
    if (e >= NEDGES) return;
    int s = ei[e], d = ei[NEDGES + e];
    int pos = atomicAdd(&cursor[d], 1);
    int slot = rowstart[d] + pos;
    csrc[slot] = s;
    float ds = fmaxf(deg[s], 1.0f), dd = fmaxf(deg[d], 1.0f);
    cnrm[slot] = 1.0f / sqrtf(ds * dd);
}

// --------------------------------- agg_x = gather-sum of x (f32 in, bf16 out)
__global__ void k_aggx(const float* __restrict__ x, const int* __restrict__ rowstart,
                       const int* __restrict__ csrc, const float* __restrict__ cnrm,
                       u16* __restrict__ aggx) {
    int gid = blockIdx.x * 256 + threadIdx.x;
    if (gid >= NNODES * 32) return;
    int c4 = gid & 31, node = gid >> 5;
    int r0 = rowstart[node], r1 = rowstart[node + 1];
    float ax = 0.f, ay = 0.f, az = 0.f, aw = 0.f;
    for (int j = r0; j < r1; ++j) {
        int s = csrc[j];
        float wv = cnrm[j];
        float4 v = ((const float4*)(x + (size_t)s * DFEAT))[c4];
        ax += wv * v.x; ay += wv * v.y; az += wv * v.z; aw += wv * v.w;
    }
    uint2 o;
    o.x = ((unsigned)f2bf(ay) << 16) | f2bf(ax);
    o.y = ((unsigned)f2bf(aw) << 16) | f2bf(az);
    ((uint2*)(aggx + (size_t)node * DFEAT))[c4] = o;
}

// -------- GEMM1: h[e] = relu(aggx @ W1[e] + b1[e]); wave = 16 rows x 64 cols
// grid (313, 8): y = e*2 + chalf; 10016 waves (~2.45/SIMD)
__launch_bounds__(256)
__global__ void k_gemm1(const u16* __restrict__ aggx, const u16* __restrict__ W1t,
                        const float* __restrict__ b1, u16* __restrict__ h) {
    int e = blockIdx.y >> 1, ch = blockIdx.y & 1;
    int w = threadIdx.x >> 6, l = threadIdx.x & 63;
    int rbase = (blockIdx.x * 4 + w) * 16;         // up to 20016 (tail guarded)
    int lr = l & 15, kg = l >> 4;

    const short8v* A8 = (const short8v*)aggx;
    const short8v* B8 = (const short8v*)(W1t + (size_t)e * 16384 + (size_t)ch * 64 * 128);

    short8v a[4];
#pragma unroll
    for (int kk = 0; kk < 4; ++kk) a[kk] = A8[(size_t)(rbase + lr) * 16 + kk * 4 + kg];

    u16* hb = h + (size_t)e * NNODES * DFEAT;
#pragma unroll
    for (int c = 0; c < 4; ++c) {
        float4v acc = {0.f, 0.f, 0.f, 0.f};
#pragma unroll
        for (int kk = 0; kk < 4; ++kk) {
            short8v b = B8[(c * 16 + lr) * 16 + kk * 4 + kg];
            acc = __builtin_amdgcn_mfma_f32_16x16x32_bf16(a[kk], b, acc, 0, 0, 0);
        }
        float bv = b1[e * DFEAT + ch * 64 + c * 16 + lr];
#pragma unroll
        for (int i = 0; i < 4; ++i) {
            int node = rbase + kg * 4 + i;
            if (node < NNODES) {
                float vv = fmaxf(acc[i] + bv, 0.f);
                hb[(size_t)node * DFEAT + ch * 64 + c * 16 + lr] = f2bf(vv);
            }
        }
    }
}

// ------------- agg_h gather (bf16 in/out), SKIPPING gated-off (e,node) pairs
__global__ void k_aggh(const u16* __restrict__ h, const int* __restrict__ rowstart,
                       const int* __restrict__ csrc, const float* __restrict__ cnrm,
                       const float* __restrict__ gates, u16* __restrict__ aggh) {
    int gid = blockIdx.x * 256 + threadIdx.x;
    if (gid >= NEXP * NNODES * 16) return;
    int l8 = gid & 15;
    int ni = gid >> 4;
    int node = ni % NNODES;
    int e = ni / NNODES;
    if (gates[(size_t)node * 4 + e] == 0.0f) return;  // contribution multiplied by 0 later
    const u16* hb = h + (size_t)e * NNODES * DFEAT;
    int r0 = rowstart[node], r1 = rowstart[node + 1];
    float a0 = 0.f, a1 = 0.f, a2 = 0.f, a3 = 0.f, a4 = 0.f, a5 = 0.f, a6 = 0.f, a7 = 0.f;
    for (int j = r0; j < r1; ++j) {
        int s = csrc[j];
        float wv = cnrm[j];
        uint4 v = ((const uint4*)(hb + (size_t)s * DFEAT))[l8];
        a0 += wv * lo2f(v.x); a1 += wv * hi2f(v.x);
        a2 += wv * lo2f(v.y); a3 += wv * hi2f(v.y);
        a4 += wv * lo2f(v.z); a5 += wv * hi2f(v.z);
        a6 += wv * lo2f(v.w); a7 += wv * hi2f(v.w);
    }
    uint4 o;
    o.x = ((unsigned)f2bf(a1) << 16) | f2bf(a0);
    o.y = ((unsigned)f2bf(a3) << 16) | f2bf(a2);
    o.z = ((unsigned)f2bf(a5) << 16) | f2bf(a4);
    o.w = ((unsigned)f2bf(a7) << 16) | f2bf(a6);
    ((uint4*)(aggh + (size_t)ni * DFEAT))[l8] = o;
}

// ---- GEMM2 fused gate-combine (+ loss in (0,0,0)); wave = 16 rows x 16 cols
// grid (313, 8): y = c-frag; 10016 waves; expert loop + combine in registers
__launch_bounds__(256)
__global__ void k_gemm2(const u16* __restrict__ aggh, const u16* __restrict__ W2t,
                        const float* __restrict__ b2, const float* __restrict__ gates,
                        const float* __restrict__ importance, float* __restrict__ out) {
    if (blockIdx.x == 0 && blockIdx.y == 0 && threadIdx.x == 0) {
        float v0 = importance[0], v1 = importance[1], v2 = importance[2], v3 = importance[3];
        float mean = 0.25f * (v0 + v1 + v2 + v3);
        float d0 = v0 - mean, d1 = v1 - mean, d2 = v2 - mean, d3 = v3 - mean;
        float var = 0.25f * (d0 * d0 + d1 * d1 + d2 * d2 + d3 * d3);
        out[(size_t)NNODES * DFEAT] = 0.01f * var / (mean * mean + 1e-10f);
    }
    int w = threadIdx.x >> 6, l = threadIdx.x & 63;
    int rbase = (blockIdx.x * 4 + w) * 16;
    int cf = blockIdx.y;
    int lr = l & 15, kg = l >> 4;

    float4v acc = {0.f, 0.f, 0.f, 0.f};

#pragma unroll
    for (int e = 0; e < NEXP; ++e) {
        const short8v* A8 = (const short8v*)(aggh + (size_t)e * NNODES * DFEAT);
        const short8v* B8 = (const short8v*)(W2t + (size_t)e * 16384);
        short8v a[4];
#pragma unroll
        for (int kk = 0; kk < 4; ++kk) a[kk] = A8[(size_t)(rbase + lr) * 16 + kk * 4 + kg];
        float g[4];
#pragma unroll
        for (int i = 0; i < 4; ++i) g[i] = gates[(size_t)(rbase + kg * 4 + i) * 4 + e];
        float4v t = {0.f, 0.f, 0.f, 0.f};
#pragma unroll
        for (int kk = 0; kk < 4; ++kk) {
            short8v b = B8[(cf * 16 + lr) * 16 + kk * 4 + kg];
            t = __builtin_amdgcn_mfma_f32_16x16x32_bf16(a[kk], b, t, 0, 0, 0);
        }
        float bv = b2[e * DFEAT + cf * 16 + lr];
#pragma unroll
        for (int i = 0; i < 4; ++i) acc[i] += g[i] * (t[i] + bv);
    }

#pragma unroll
    for (int i = 0; i < 4; ++i) {
        int node = rbase + kg * 4 + i;
        if (node < NNODES) out[(size_t)node * DFEAT + cf * 16 + lr] = acc[i];
    }
}

// --------------------------------------------------------------- launcher
extern "C" void kernel_launch(void* const* d_in, const int* in_sizes, int n_in,
                              void* d_out, int out_size, void* d_ws, size_t ws_size,
                              hipStream_t stream) {
    const float* x      = (const float*)d_in[0];
    const int*   ei     = (const int*)d_in[1];
    const float* x_agg  = (const float*)d_in[2];
    const float* w_gate = (const float*)d_in[3];
    const float* thr    = (const float*)d_in[4];
    const float* mask   = (const float*)d_in[5];
    const float* W1     = (const float*)d_in[6];
    const float* b1     = (const float*)d_in[7];
    const float* W2     = (const float*)d_in[8];
    const float* b2     = (const float*)d_in[9];
    float* out = (float*)d_out;
    float* ws  = (float*)d_ws;

    float* deg        = ws;
    int*   cursor     = (int*)(ws + 20000);
    float* importance = ws + 40000;
    int*   rowstart   = (int*)(ws + 40960);
    int*   csrc       = (int*)(ws + 61440);
    float* cnrm       = ws + 221440;
    float* gates      = ws + 381440;
    u16*   W1t        = (u16*)(ws + 461440);
    u16*   W2t        = (u16*)(ws + 494208);
    u16*   aggx       = (u16*)(ws + 526976);
    u16*   h          = (u16*)(ws + 1806976);
    u16*   aggh       = (u16*)(ws + 6926976);

    hipMemsetAsync(d_ws, 0, 40008 * sizeof(float), stream);

    k_pre<<<832, 256, 0, stream>>>(ei, W1, W2, x_agg, w_gate, thr, mask,
                                   deg, W1t, W2t, gates, importance);
    k_scan<<<1, 1024, 0, stream>>>(deg, rowstart);
    k_fill<<<(NEDGES + 255) / 256, 256, 0, stream>>>(ei, deg, rowstart, cursor, csrc, cnrm);
    k_aggx<<<(NNODES * 32) / 256, 256, 0, stream>>>(x, rowstart, csrc, cnrm, aggx);
    k_gemm1<<<dim3(313, 8), 256, 0, stream>>>(aggx, W1t, b1, h);
    k_aggh<<<(NEXP * NNODES * 16) / 256, 256, 0, stream>>>(h, rowstart, csrc, cnrm, gates, aggh);
    k_gemm2<<<dim3(313, 8), 256, 0, stream>>>(aggh, W2t, b2, gates, importance, out);
}

// Round 9
// 242.540 us; speedup vs baseline: 1.1208x; 1.1208x over previous
//
#include <hip/hip_runtime.h>
#include <cstdint>
#include <cstddef>

#define NNODES 20000
#define NEDGES 160000
#define DFEAT  128
#define NEXP   4

typedef unsigned short u16;
typedef __attribute__((ext_vector_type(8))) short short8v;   // 8 bf16 (4 VGPRs)
typedef __attribute__((ext_vector_type(4))) float float4v;   // 4 f32 acc

static __device__ __forceinline__ u16 f2bf(float f) {
    union { float f; unsigned int i; } v; v.f = f;
    unsigned int r = (v.i + 0x7FFFu + ((v.i >> 16) & 1u)) >> 16;  // RNE
    return (u16)r;
}
static __device__ __forceinline__ unsigned pack2(float a, float b) {
    return ((unsigned)f2bf(b) << 16) | f2bf(a);
}
static __device__ __forceinline__ float lo2f(unsigned int u) { return __uint_as_float(u << 16); }
static __device__ __forceinline__ float hi2f(unsigned int u) { return __uint_as_float(u & 0xFFFF0000u); }

static __device__ __forceinline__ void acc8(float w, uint4 v, float* a) {
    a[0] += w * lo2f(v.x); a[1] += w * hi2f(v.x);
    a[2] += w * lo2f(v.y); a[3] += w * hi2f(v.y);
    a[4] += w * lo2f(v.z); a[5] += w * hi2f(v.z);
    a[6] += w * lo2f(v.w); a[7] += w * hi2f(v.w);
}

// ---------------- workspace layout (float-element offsets; all 16B-aligned) --
// deg        0        [20000]  (zeroed)
// cursor     20000    [20000]  (zeroed)
// importance 40000    [8]      (zeroed)
// rowstart   40960    [20001] int
// csrc       61440    [160000] int
// cnrm       221440   [160000]
// gates      381440   [80000]
// W1t        461440   (65536 u16)  bf16 [4][128c][128k]
// W2t        494208   (65536 u16)
// xbf        526976   (2.56M u16)  bf16 [20000][128]
// aggx       1806976  (2.56M u16)  bf16 [20000][128]
// h          3086976  (10.24M u16) bf16 [4][20000][128]
// aggh       8206976  (10.24M u16) bf16 [4][20000][128]
// end        13326976 floats = 53.3 MB

// ---- fused independent pre-work: deg | transpose(W) | gate | x->bf16 --------
// blocks [0,625): degree; [625,753): W transpose; [753,832): gate; [832,2082): xconv
__global__ void k_pre(const int* __restrict__ ei, const float* __restrict__ x,
                      const float* __restrict__ W1, const float* __restrict__ W2,
                      const float* __restrict__ x_agg, const float* __restrict__ w_gate,
                      const float* __restrict__ thr, const float* __restrict__ mask,
                      float* __restrict__ deg, u16* __restrict__ W1t, u16* __restrict__ W2t,
                      float* __restrict__ gates, float* __restrict__ importance,
                      u16* __restrict__ xbf) {
    int b = blockIdx.x;
    if (b < 625) {                       // ---- degree histogram
        int e = b * 256 + threadIdx.x;
        if (e < NEDGES) atomicAdd(&deg[ei[NEDGES + e]], 1.0f);
        return;
    }
    if (b < 753) {                       // ---- coalesced W transpose + bf16
        __shared__ u16 tile[32][33];
        int tb = b - 625;                // 0..127
        int arr = tb >> 6;
        int t6 = tb & 63;                // e(2) | ktile(2) | ctile(2)
        int e  = t6 >> 4;
        int kt = (t6 >> 2) & 3;
        int ct = t6 & 3;
        const float* W = arr ? W2 : W1;
        u16* Wt = arr ? W2t : W1t;
        int ty = threadIdx.x >> 5, tx = threadIdx.x & 31;
#pragma unroll
        for (int r = 0; r < 4; ++r) {    // read W[k][c] coalesced in c
            int k = kt * 32 + ty + r * 8;
            int c = ct * 32 + tx;
            tile[ty + r * 8][tx] = f2bf(W[(size_t)e * 16384 + (size_t)k * 128 + c]);
        }
        __syncthreads();
#pragma unroll
        for (int r = 0; r < 4; ++r) {    // write Wt[c][k] coalesced in k
            int c = ct * 32 + ty + r * 8;
            int k = kt * 32 + tx;
            Wt[(size_t)e * 16384 + (size_t)c * 128 + k] = tile[tx][ty + r * 8];
        }
        return;
    }
    if (b < 832) {                       // ---- gating (f32 exact)
        int n = (b - 753) * 256 + threadIdx.x;
        float4 lg = make_float4(0.f, 0.f, 0.f, 0.f);
        if (n < NNODES) {
            const float4* xr = (const float4*)(x_agg + (size_t)n * DFEAT);
            const float4* wg = (const float4*)w_gate;
            for (int k4 = 0; k4 < 32; ++k4) {
                float4 xv = xr[k4];
                float4 w0 = wg[4 * k4 + 0], w1 = wg[4 * k4 + 1];
                float4 w2 = wg[4 * k4 + 2], w3 = wg[4 * k4 + 3];
                lg.x += xv.x * w0.x + xv.y * w1.x + xv.z * w2.x + xv.w * w3.x;
                lg.y += xv.x * w0.y + xv.y * w1.y + xv.z * w2.y + xv.w * w3.y;
                lg.z += xv.x * w0.z + xv.y * w1.z + xv.z * w2.z + xv.w * w3.z;
                lg.w += xv.x * w0.w + xv.y * w1.w + xv.z * w2.w + xv.w * w3.w;
            }
        }
        float g[4];
        float lv[4] = {lg.x, lg.y, lg.z, lg.w};
        for (int e = 0; e < 4; ++e) {
            float sgm = 1.0f / (1.0f + expf(-lv[e]));
            g[e] = (sgm - thr[e] > 0.0f) ? mask[e] : 0.0f;
            if (n >= NNODES) g[e] = 0.0f;
        }
        if (n < NNODES) ((float4*)gates)[n] = make_float4(g[0], g[1], g[2], g[3]);
        int lane = threadIdx.x & 63;
        for (int e = 0; e < 4; ++e) {
            float v = g[e];
            for (int off = 32; off >= 1; off >>= 1) v += __shfl_down(v, off);
            if (lane == 0) atomicAdd(&importance[e], v);
        }
        return;
    }
    // ---- x -> bf16 (8 floats per thread)
    int t8 = (b - 832) * 256 + threadIdx.x;       // [0, 320000)
    const float4* xr = (const float4*)x + (size_t)t8 * 2;
    float4 v0 = xr[0], v1 = xr[1];
    uint4 o;
    o.x = pack2(v0.x, v0.y); o.y = pack2(v0.z, v0.w);
    o.z = pack2(v1.x, v1.y); o.w = pack2(v1.z, v1.w);
    ((uint4*)xbf)[t8] = o;
}

// ------------------------------------------------- exclusive scan (1 block)
__global__ void k_scan(const float* __restrict__ deg, int* __restrict__ rowstart) {
    __shared__ int part[1024];
    int t = threadIdx.x;
    const int PER = 20;
    int base = t * PER;
    int s = 0;
    for (int i = 0; i < PER; ++i) {
        int n = base + i;
        if (n < NNODES) s += (int)deg[n];
    }
    part[t] = s;
    __syncthreads();
    for (int off = 1; off < 1024; off <<= 1) {
        int v = (t >= off) ? part[t - off] : 0;
        __syncthreads();
        part[t] += v;
        __syncthreads();
    }
    int run = part[t] - s;
    for (int i = 0; i < PER; ++i) {
        int n = base + i;
        if (n < NNODES) {
            rowstart[n] = run;
            run += (int)deg[n];
        }
    }
    if (t == 1023) rowstart[NNODES] = part[1023];
}

// ------------------------------------------------------- CSR fill + norm
__global__ void k_fill(const int* __restrict__ ei, const float* __restrict__ deg,
                       const int* __restrict__ rowstart, int* __restrict__ cursor,
                       int* __restrict__ csrc, float* __restrict__ cnrm) {
    int e = blockIdx.x * 256 + threadIdx.x;
    if (e >= NEDGES) return;
    int s = ei[e], d = ei[NEDGES + e];
    int pos = atomicAdd(&cursor[d], 1);
    int slot = rowstart[d] + pos;
    csrc[slot] = s;
    float ds = fmaxf(deg[s], 1.0f), dd = fmaxf(deg[d], 1.0f);
    cnrm[slot] = 1.0f / sqrtf(ds * dd);
}

// ---- agg_x gather (bf16 in/out), 16 lanes/node, 4-deep MLP edge batching ----
__global__ void k_aggx(const u16* __restrict__ xbf, const int* __restrict__ rowstart,
                       const int* __restrict__ csrc, const float* __restrict__ cnrm,
                       u16* __restrict__ aggx) {
    int gid = blockIdx.x * 256 + threadIdx.x;
    if (gid >= NNODES * 16) return;
    int l8 = gid & 15, node = gid >> 4;
    int r0 = rowstart[node], r1 = rowstart[node + 1];
    float a[8] = {0.f, 0.f, 0.f, 0.f, 0.f, 0.f, 0.f, 0.f};
    int j = r0;
    for (; j + 4 <= r1; j += 4) {
        int s0 = csrc[j], s1 = csrc[j + 1], s2 = csrc[j + 2], s3 = csrc[j + 3];
        float w0 = cnrm[j], w1 = cnrm[j + 1], w2 = cnrm[j + 2], w3 = cnrm[j + 3];
        uint4 v0 = ((const uint4*)(xbf + (size_t)s0 * DFEAT))[l8];
        uint4 v1 = ((const uint4*)(xbf + (size_t)s1 * DFEAT))[l8];
        uint4 v2 = ((const uint4*)(xbf + (size_t)s2 * DFEAT))[l8];
        uint4 v3 = ((const uint4*)(xbf + (size_t)s3 * DFEAT))[l8];
        acc8(w0, v0, a); acc8(w1, v1, a); acc8(w2, v2, a); acc8(w3, v3, a);
    }
    for (; j < r1; ++j) {
        int s = csrc[j];
        float w = cnrm[j];
        uint4 v = ((const uint4*)(xbf + (size_t)s * DFEAT))[l8];
        acc8(w, v, a);
    }
    uint4 o;
    o.x = pack2(a[0], a[1]); o.y = pack2(a[2], a[3]);
    o.z = pack2(a[4], a[5]); o.w = pack2(a[6], a[7]);
    ((uint4*)(aggx + (size_t)node * DFEAT))[l8] = o;
}

// ----------------------------------- GEMM1: h[e] = relu(aggx @ W1[e] + b1[e])
// grid (250, 4 experts) x 320 thr; wave = 16 rows x 128 cols; no LDS
__launch_bounds__(320)
__global__ void k_gemm1(const u16* __restrict__ aggx, const u16* __restrict__ W1t,
                        const float* __restrict__ b1, u16* __restrict__ h) {
    int e = blockIdx.y;
    int w = threadIdx.x >> 6, l = threadIdx.x & 63;
    int rbase = blockIdx.x * 80 + w * 16;
    int lr = l & 15, kg = l >> 4;

    const short8v* A8 = (const short8v*)aggx;
    const short8v* B8 = (const short8v*)(W1t + (size_t)e * 16384);

    short8v a[4];
#pragma unroll
    for (int kk = 0; kk < 4; ++kk) a[kk] = A8[(size_t)(rbase + lr) * 16 + kk * 4 + kg];

    u16* hb = h + (size_t)e * NNODES * DFEAT;
#pragma unroll
    for (int c = 0; c < 8; ++c) {
        float4v acc = {0.f, 0.f, 0.f, 0.f};
#pragma unroll
        for (int kk = 0; kk < 4; ++kk) {
            short8v b = B8[(c * 16 + lr) * 16 + kk * 4 + kg];
            acc = __builtin_amdgcn_mfma_f32_16x16x32_bf16(a[kk], b, acc, 0, 0, 0);
        }
        float bv = b1[e * DFEAT + c * 16 + lr];
#pragma unroll
        for (int i = 0; i < 4; ++i) {
            int node = rbase + kg * 4 + i;
            float vv = fmaxf(acc[i] + bv, 0.f);
            hb[(size_t)node * DFEAT + c * 16 + lr] = f2bf(vv);
        }
    }
}

// ---- agg_h gather (bf16 in/out), gate-skip + 4-deep MLP edge batching -------
__global__ void k_aggh(const u16* __restrict__ h, const int* __restrict__ rowstart,
                       const int* __restrict__ csrc, const float* __restrict__ cnrm,
                       const float* __restrict__ gates, u16* __restrict__ aggh) {
    int gid = blockIdx.x * 256 + threadIdx.x;
    if (gid >= NEXP * NNODES * 16) return;
    int l8 = gid & 15;
    int ni = gid >> 4;
    int node = ni % NNODES;
    int e = ni / NNODES;
    if (gates[(size_t)node * 4 + e] == 0.0f) return;  // multiplied by 0 later
    const u16* hb = h + (size_t)e * NNODES * DFEAT;
    int r0 = rowstart[node], r1 = rowstart[node + 1];
    float a[8] = {0.f, 0.f, 0.f, 0.f, 0.f, 0.f, 0.f, 0.f};
    int j = r0;
    for (; j + 4 <= r1; j += 4) {
        int s0 = csrc[j], s1 = csrc[j + 1], s2 = csrc[j + 2], s3 = csrc[j + 3];
        float w0 = cnrm[j], w1 = cnrm[j + 1], w2 = cnrm[j + 2], w3 = cnrm[j + 3];
        uint4 v0 = ((const uint4*)(hb + (size_t)s0 * DFEAT))[l8];
        uint4 v1 = ((const uint4*)(hb + (size_t)s1 * DFEAT))[l8];
        uint4 v2 = ((const uint4*)(hb + (size_t)s2 * DFEAT))[l8];
        uint4 v3 = ((const uint4*)(hb + (size_t)s3 * DFEAT))[l8];
        acc8(w0, v0, a); acc8(w1, v1, a); acc8(w2, v2, a); acc8(w3, v3, a);
    }
    for (; j < r1; ++j) {
        int s = csrc[j];
        float w = cnrm[j];
        uint4 v = ((const uint4*)(hb + (size_t)s * DFEAT))[l8];
        acc8(w, v, a);
    }
    uint4 o;
    o.x = pack2(a[0], a[1]); o.y = pack2(a[2], a[3]);
    o.z = pack2(a[4], a[5]); o.w = pack2(a[6], a[7]);
    ((uint4*)(aggh + (size_t)ni * DFEAT))[l8] = o;
}

// ------------- GEMM2 fused gate-combine (+ load-loss in thread (0,0))
// grid (250, 4 col-splits) x 320 thr; wave = 16 rows x 32 cols; no LDS
__launch_bounds__(320)
__global__ void k_gemm2(const u16* __restrict__ aggh, const u16* __restrict__ W2t,
                        const float* __restrict__ b2, const float* __restrict__ gates,
                        const float* __restrict__ importance, float* __restrict__ out) {
    if (blockIdx.x == 0 && blockIdx.y == 0 && threadIdx.x == 0) {
        float v0 = importance[0], v1 = importance[1], v2 = importance[2], v3 = importance[3];
        float mean = 0.25f * (v0 + v1 + v2 + v3);
        float d0 = v0 - mean, d1 = v1 - mean, d2 = v2 - mean, d3 = v3 - mean;
        float var = 0.25f * (d0 * d0 + d1 * d1 + d2 * d2 + d3 * d3);
        out[(size_t)NNODES * DFEAT] = 0.01f * var / (mean * mean + 1e-10f);
    }
    int w = threadIdx.x >> 6, l = threadIdx.x & 63;
    int rbase = blockIdx.x * 80 + w * 16;
    int cb = blockIdx.y * 2;
    int lr = l & 15, kg = l >> 4;

    float4v acc[2];
    acc[0] = (float4v){0.f, 0.f, 0.f, 0.f};
    acc[1] = (float4v){0.f, 0.f, 0.f, 0.f};

#pragma unroll
    for (int e = 0; e < NEXP; ++e) {
        const short8v* A8 = (const short8v*)(aggh + (size_t)e * NNODES * DFEAT);
        const short8v* B8 = (const short8v*)(W2t + (size_t)e * 16384);
        short8v a[4];
#pragma unroll
        for (int kk = 0; kk < 4; ++kk) a[kk] = A8[(size_t)(rbase + lr) * 16 + kk * 4 + kg];
        float g[4];
#pragma unroll
        for (int i = 0; i < 4; ++i) g[i] = gates[(size_t)(rbase + kg * 4 + i) * 4 + e];
#pragma unroll
        for (int c = 0; c < 2; ++c) {
            float4v t = {0.f, 0.f, 0.f, 0.f};
#pragma unroll
            for (int kk = 0; kk < 4; ++kk) {
                short8v b = B8[((cb + c) * 16 + lr) * 16 + kk * 4 + kg];
                t = __builtin_amdgcn_mfma_f32_16x16x32_bf16(a[kk], b, t, 0, 0, 0);
            }
            float bv = b2[e * DFEAT + (cb + c) * 16 + lr];
#pragma unroll
            for (int i = 0; i < 4; ++i) acc[c][i] += g[i] * (t[i] + bv);
        }
    }

#pragma unroll
    for (int c = 0; c < 2; ++c)
#pragma unroll
        for (int i = 0; i < 4; ++i) {
            int node = rbase + kg * 4 + i;
            out[(size_t)node * DFEAT + (cb + c) * 16 + lr] = acc[c][i];
        }
}

// --------------------------------------------------------------- launcher
extern "C" void kernel_launch(void* const* d_in, const int* in_sizes, int n_in,
                              void* d_out, int out_size, void* d_ws, size_t ws_size,
                              hipStream_t stream) {
    const float* x      = (const float*)d_in[0];
    const int*   ei     = (const int*)d_in[1];
    const float* x_agg  = (const float*)d_in[2];
    const float* w_gate = (const float*)d_in[3];
    const float* thr    = (const float*)d_in[4];
    const float* mask   = (const float*)d_in[5];
    const float* W1     = (const float*)d_in[6];
    const float* b1     = (const float*)d_in[7];
    const float* W2     = (const float*)d_in[8];
    const float* b2     = (const float*)d_in[9];
    float* out = (float*)d_out;
    float* ws  = (float*)d_ws;

    float* deg        = ws;
    int*   cursor     = (int*)(ws + 20000);
    float* importance = ws + 40000;
    int*   rowstart   = (int*)(ws + 40960);
    int*   csrc       = (int*)(ws + 61440);
    float* cnrm       = ws + 221440;
    float* gates      = ws + 381440;
    u16*   W1t        = (u16*)(ws + 461440);
    u16*   W2t        = (u16*)(ws + 494208);
    u16*   xbf        = (u16*)(ws + 526976);
    u16*   aggx       = (u16*)(ws + 1806976);
    u16*   h          = (u16*)(ws + 3086976);
    u16*   aggh       = (u16*)(ws + 8206976);

    hipMemsetAsync(d_ws, 0, 40008 * sizeof(float), stream);

    k_pre<<<2082, 256, 0, stream>>>(ei, x, W1, W2, x_agg, w_gate, thr, mask,
                                    deg, W1t, W2t, gates, importance, xbf);
    k_scan<<<1, 1024, 0, stream>>>(deg, rowstart);
    k_fill<<<(NEDGES + 255) / 256, 256, 0, stream>>>(ei, deg, rowstart, cursor, csrc, cnrm);
    k_aggx<<<(NNODES * 16) / 256, 256, 0, stream>>>(xbf, rowstart, csrc, cnrm, aggx);
    k_gemm1<<<dim3(250, NEXP), 320, 0, stream>>>(aggx, W1t, b1, h);
    k_aggh<<<(NEXP * NNODES * 16) / 256, 256, 0, stream>>>(h, rowstart, csrc, cnrm, gates, aggh);
    k_gemm2<<<dim3(250, 4), 320, 0, stream>>>(aggh, W2t, b2, gates, importance, out);
}